// Round 15
// baseline (2746.254 us; speedup 1.0000x reference)
//
#include <hip/hip_runtime.h>
#include <stdint.h>

// Problem constants
#define T_    256
#define B_    4
#define U_    64
#define EENC  1024
#define EDEC  640
#define J_    640
#define V_    4096

typedef unsigned short u16;
typedef unsigned int   u32;
typedef __bf16 bf16x8 __attribute__((ext_vector_type(8)));
typedef short  s16x8  __attribute__((ext_vector_type(8)));
typedef float  f32x4  __attribute__((ext_vector_type(4)));

__device__ __forceinline__ u16 f2bf(float f) {
    u32 u = __builtin_bit_cast(u32, f);
    u = (u + 0x7FFFu + ((u >> 16) & 1u)) >> 16;
    return (u16)u;
}
__device__ __forceinline__ float bf2f(u16 b) {
    return __builtin_bit_cast(float, (u32)b << 16);
}

// ---------------- f32 -> bf16 convert (vectorized x4) ----------------
__global__ __launch_bounds__(256) void cvt_bf16(const float* __restrict__ src,
                                                u16* __restrict__ dst, int n4) {
    int i = blockIdx.x * 256 + threadIdx.x;
    if (i < n4) {
        float4 v = reinterpret_cast<const float4*>(src)[i];
        ushort4 o;
        o.x = f2bf(v.x); o.y = f2bf(v.y); o.z = f2bf(v.z); o.w = f2bf(v.w);
        reinterpret_cast<ushort4*>(dst)[i] = o;
    }
}

// ---------------- LayerNorm over J=640 + bias + affine, bf16 out, transposed ----------------
__global__ __launch_bounds__(256) void ln_kernel(const float* __restrict__ proj,
                                                 const float* __restrict__ bias,
                                                 const float* __restrict__ gamma,
                                                 const float* __restrict__ beta,
                                                 u16* __restrict__ out,
                                                 int BDIM, int OUTER) {
    int pr = blockIdx.x;
    int b = pr % BDIM, outer = pr / BDIM;
    const float* row = proj + (size_t)pr * J_;
    int tid = threadIdx.x;

    float x0 = row[tid] + bias[tid];
    float x1 = row[tid + 256] + bias[tid + 256];
    float x2 = 0.f;
    bool has3 = (tid < J_ - 512);
    if (has3) x2 = row[tid + 512] + bias[tid + 512];

    float s1 = x0 + x1 + x2;
    float s2 = x0 * x0 + x1 * x1 + x2 * x2;
    for (int off = 32; off; off >>= 1) {
        s1 += __shfl_down(s1, off, 64);
        s2 += __shfl_down(s2, off, 64);
    }
    __shared__ float ws1[4], ws2[4];
    int w = tid >> 6, lane = tid & 63;
    if (lane == 0) { ws1[w] = s1; ws2[w] = s2; }
    __syncthreads();
    float S1 = ws1[0] + ws1[1] + ws1[2] + ws1[3];
    float S2 = ws2[0] + ws2[1] + ws2[2] + ws2[3];
    float mu = S1 * (1.f / J_);
    float var = S2 * (1.f / J_) - mu * mu;
    float inv = 1.0f / sqrtf(var + 1e-5f);

    size_t orow = ((size_t)b * OUTER + outer) * J_;
    out[orow + tid]       = f2bf((x0 - mu) * inv * gamma[tid]       + beta[tid]);
    out[orow + tid + 256] = f2bf((x1 - mu) * inv * gamma[tid + 256] + beta[tid + 256]);
    if (has3)
        out[orow + tid + 512] = f2bf((x2 - mu) * inv * gamma[tid + 512] + beta[tid + 512]);
}

// ---------------- joint materialization: relu(enc[b,t,:] + dec[b,u,:]) -> bf16 [B*T*U][J] ----------------
__global__ __launch_bounds__(256) void joint_mat(const u16* __restrict__ encln,
                                                 const u16* __restrict__ decln,
                                                 u16* __restrict__ joint) {
    int g = blockIdx.x * 256 + threadIdx.x;
    int row = g / (J_ / 8);
    int jc = g - row * (J_ / 8);
    int b = row >> 14;
    int t = (row >> 6) & (T_ - 1);
    int u = row & (U_ - 1);
    s16x8 e = *reinterpret_cast<const s16x8*>(encln + ((size_t)(b * T_ + t)) * J_ + jc * 8);
    s16x8 d = *reinterpret_cast<const s16x8*>(decln + ((size_t)(b * U_ + u)) * J_ + jc * 8);
    s16x8 o;
#pragma unroll
    for (int k = 0; k < 8; ++k) {
        float v = bf2f((u16)e[k]) + bf2f((u16)d[k]);
        o[k] = (short)f2bf(fmaxf(v, 0.f));
    }
    *reinterpret_cast<s16x8*>(joint + (size_t)row * J_ + jc * 8) = o;
}

// ---------------- m97-structure 128x128 GEMM (stage-1 projections) ----------------
__global__ __launch_bounds__(256) void gemm_bt(const u16* __restrict__ A,
                                               const u16* __restrict__ Bt,
                                               float* __restrict__ C,
                                               const float* __restrict__ bias,
                                               int K, int ldc) {
    __shared__ u16 As[128 * 64];
    __shared__ u16 Bs[128 * 64];
    const int tid = threadIdx.x;
    const int w = tid >> 6, lane = tid & 63;
    const int wr = w >> 1, wc = w & 1;
    const size_t m0 = (size_t)blockIdx.y * 128;
    const size_t n0 = (size_t)blockIdx.x * 128;

    f32x4 acc[4][4] = {};

    const int l3 = lane >> 3;
    const int c8 = (lane & 7) * 8;
    const int nkt = K >> 6;

    for (int kt = 0; kt < nkt; ++kt) {
        if (kt) __syncthreads();
        const int k0 = kt << 6;
#pragma unroll
        for (int i = 0; i < 4; ++i) {
            const int c = w * 4 + i;
            const int r = c * 8 + l3;
            const u16* ga = A  + (m0 + r) * (size_t)K + k0 + c8;
            const u16* gb = Bt + (n0 + r) * (size_t)K + k0 + c8;
            __builtin_amdgcn_global_load_lds(
                (const __attribute__((address_space(1))) void*)ga,
                (__attribute__((address_space(3))) void*)(As + c * 512), 16, 0, 0);
            __builtin_amdgcn_global_load_lds(
                (const __attribute__((address_space(1))) void*)gb,
                (__attribute__((address_space(3))) void*)(Bs + c * 512), 16, 0, 0);
        }
        __syncthreads();

#pragma unroll
        for (int kk = 0; kk < 2; ++kk) {
            bf16x8 af[4], bfr[4];
#pragma unroll
            for (int i = 0; i < 4; ++i) {
                int ra = wr * 64 + i * 16 + (lane & 15);
                af[i] = *reinterpret_cast<const bf16x8*>(As + ra * 64 + kk * 32 + (lane >> 4) * 8);
                int rb = wc * 64 + i * 16 + (lane & 15);
                bfr[i] = *reinterpret_cast<const bf16x8*>(Bs + rb * 64 + kk * 32 + (lane >> 4) * 8);
            }
#pragma unroll
            for (int i = 0; i < 4; ++i)
#pragma unroll
                for (int j = 0; j < 4; ++j)
                    acc[i][j] = __builtin_amdgcn_mfma_f32_16x16x32_bf16(af[i], bfr[j], acc[i][j], 0, 0, 0);
        }
    }

    const int r4 = (lane >> 4) * 4;
    const int cl = lane & 15;
#pragma unroll
    for (int i = 0; i < 4; ++i) {
#pragma unroll
        for (int j = 0; j < 4; ++j) {
            size_t grow = m0 + wr * 64 + i * 16 + r4;
            size_t gcol = n0 + wc * 64 + j * 16 + cl;
            float bv = bias ? bias[gcol] : 0.f;
#pragma unroll
            for (int r = 0; r < 4; ++r)
                C[(grow + r) * (size_t)ldc + gcol] = acc[i][j][r] + bv;
        }
    }
}

// ---------------- vocab projection: 128x128 tile, BK=32, 4 wgs/CU ----------------
// R15: concurrency lever. R13 counters: MfmaUtil 18%, VALUBusy 9%, HBM 37% —
// nothing busy => barrier-synchronized stalls at low wg count. 256-thr wg
// (4 waves 2x2, wave tile 64x64, acc[4][4], ~116 VGPR), dbuf LDS 33 KB,
// __launch_bounds__(256,4) -> 4 wgs/CU = 4 independent barrier domains:
// staging bursts, MFMA phases and epilogue drains interleave across wgs.
// n-ownership grid (beat m-ownership R14). Full-line nt bounce epilogue
// (beat scalar nt R13 1.73x amplification, beat cached R5/R12).
#define BKS  32
#define BIGK 640
#define BIGN 4096
#define NTS  (BIGK / BKS)
#define ASZ  (128 * BKS)     // 4096 u16 = 8 KiB per operand buffer

__global__ __launch_bounds__(256, 4) void gemm_big(const u16* __restrict__ A,
                                                   const u16* __restrict__ Bt,
                                                   float* __restrict__ C,
                                                   const float* __restrict__ bias) {
    __shared__ u16 shm[16896];   // staging 2x(A+B)=32 KiB; epilogue bounce 64x132 f32 = 33 KiB

    const int tid = threadIdx.x;
    const int w = tid >> 6, lane = tid & 63;
    const int wr = w >> 1, wc = w & 1;
    const int fr = lane & 15, fq = lane >> 4;

    // n-ownership: xcd = lin&7 owns n-tiles {4*xcd .. 4*xcd+3} (B 655 KB L2-hot);
    // n innermost -> 4 consecutive wgs share an A-tile (L2-hot after first).
    const int lin = blockIdx.x;
    const int xcd = lin & 7;
    const int idx = lin >> 3;            // 0..2047
    const size_t m0 = (size_t)(idx >> 2) * 128;
    const size_t n0 = (size_t)(xcd * 4 + (idx & 2 ? (idx & 3) : (idx & 3))) * 128;

    // staging: per call, thread covers 16 B: row = c*64 + (tid>>2), phys seg = tid&3.
    // T2 involution: source seg = phys ^ (row&3); (row+64)&3 == row&3.
    const int srow = tid >> 2;                 // 0..63
    const int sseg = (tid & 3) ^ (srow & 3);
    const u16* aga = A  + (m0 + srow) * (size_t)BIGK + sseg * 8;
    const u16* bga = Bt + (n0 + srow) * (size_t)BIGK + sseg * 8;

    f32x4 acc[4][4] = {};

    // LDS u16 offsets: buf bo: A at bo*8192, B at bo*8192+4096; call c adds c*2048.
#define STAGE(bo, k0)                                                              \
    { _Pragma("unroll")                                                            \
      for (int c = 0; c < 2; ++c) {                                                \
        __builtin_amdgcn_global_load_lds(                                          \
            (const __attribute__((address_space(1))) void*)(aga + (size_t)c * 64 * BIGK + (k0)), \
            (__attribute__((address_space(3))) void*)(&shm[(bo) * 8192 + c * 2048 + tid * 8]), 16, 0, 0); \
        __builtin_amdgcn_global_load_lds(                                          \
            (const __attribute__((address_space(1))) void*)(bga + (size_t)c * 64 * BIGK + (k0)), \
            (__attribute__((address_space(3))) void*)(&shm[(bo) * 8192 + 4096 + c * 2048 + tid * 8]), 16, 0, 0); \
      } }

    // ds_read: logical (row, colbyte=fq*16) -> physical colbyte ^ ((row&3)<<4)
#define RD_A(bo, mi)                                                               \
    (*reinterpret_cast<const bf16x8*>(&shm[(bo) * 8192 +                           \
        (wr * 64 + (mi) * 16 + fr) * BKS +                                         \
        (((fq * 16) ^ (((wr * 64 + (mi) * 16 + fr) & 3) << 4)) >> 1)]))
#define RD_B(bo, ni)                                                               \
    (*reinterpret_cast<const bf16x8*>(&shm[(bo) * 8192 + 4096 +                    \
        (wc * 64 + (ni) * 16 + fr) * BKS +                                         \
        (((fq * 16) ^ (((wc * 64 + (ni) * 16 + fr) & 3) << 4)) >> 1)]))

#define VM0   asm volatile("s_waitcnt vmcnt(0)" ::: "memory")
#define LGKM0 asm volatile("s_waitcnt lgkmcnt(0)" ::: "memory")

    // prologue
    STAGE(0, 0);
    VM0;
    __builtin_amdgcn_s_barrier();

    for (int t = 0; t < NTS; ++t) {
        const int cur = t & 1;
        const bool pf = (t + 1 < NTS);
        bf16x8 af[4], bf[4];

#pragma unroll
        for (int i = 0; i < 4; ++i) af[i] = RD_A(cur, i);
#pragma unroll
        for (int j = 0; j < 4; ++j) bf[j] = RD_B(cur, j);
        if (pf) STAGE(cur ^ 1, (t + 1) * BKS);
        LGKM0;
        __builtin_amdgcn_s_setprio(1);
#pragma unroll
        for (int i = 0; i < 4; ++i)
#pragma unroll
            for (int j = 0; j < 4; ++j)
                acc[i][j] = __builtin_amdgcn_mfma_f32_16x16x32_bf16(af[i], bf[j], acc[i][j], 0, 0, 0);
        __builtin_amdgcn_s_setprio(0);
        if (pf) {
            VM0;
            __builtin_amdgcn_s_barrier();
        }
    }

#undef STAGE
#undef RD_A
#undef RD_B
#undef VM0
#undef LGKM0

    // ---- epilogue: LDS bounce -> contiguous f32x4 nt stores ----
    // bounce: [64][132] f32 (16B-aligned rows). half = wr's 64 rows; all 4 waves
    // store: thread -> row = tid>>2 (0..63), colblock = (tid&3)*32 -> 512B bursts.
    float* bnc = reinterpret_cast<float*>(shm);
    const int brow = tid >> 2;
    const int bcb  = (tid & 3) * 32;
#pragma unroll
    for (int half = 0; half < 2; ++half) {
        __syncthreads();
        if (wr == half) {
#pragma unroll
            for (int ni = 0; ni < 4; ++ni) {
                const int col = wc * 64 + ni * 16 + fr;
                const float bv = bias[n0 + col];
#pragma unroll
                for (int mi = 0; mi < 4; ++mi) {
                    const int lr = mi * 16 + fq * 4;
#pragma unroll
                    for (int r = 0; r < 4; ++r)
                        bnc[(lr + r) * 132 + col] = acc[mi][ni][r] + bv;
                }
            }
        }
        __syncthreads();
        const size_t grow = m0 + half * 64 + brow;
        float* dst = &C[grow * (size_t)BIGN + n0 + bcb];
        const float* src = &bnc[brow * 132 + bcb];
#pragma unroll
        for (int k = 0; k < 8; ++k) {
            f32x4 v = *reinterpret_cast<const f32x4*>(src + k * 4);
            __builtin_nontemporal_store(v, reinterpret_cast<f32x4*>(dst + k * 4));
        }
    }
}

// ---------------- workspace layout (bytes) ----------------
static const size_t O_JOINT = 0;                              // bf16 [65536][640]
static const size_t O_WOUT  = 83886080;                       // bf16 [4096][640]
static const size_t O_ENCLN = 89128960;                       // bf16 [B*T][J]
static const size_t O_DECLN = 90439680;                       // bf16 [B*U][J]
static const size_t O_ENCIN = 90767360;                       // bf16 [T*B][EENC]
static const size_t O_DECIN = 92864512;                       // bf16 [U*B][EDEC]
static const size_t O_WENC  = 93192192;                       // bf16 [J][EENC]
static const size_t O_WDEC  = 94502912;                       // bf16 [J][EDEC]
static const size_t O_EPROJ = 95322112;                       // f32  [T*B][J]
static const size_t O_DPROJ = 97943552;                       // f32  [U*B][J]
static const size_t WS_NEEDED = 98598912;

extern "C" void kernel_launch(void* const* d_in, const int* in_sizes, int n_in,
                              void* d_out, int out_size, void* d_ws, size_t ws_size,
                              hipStream_t stream) {
    const float* enc   = (const float*)d_in[0];
    const float* dec   = (const float*)d_in[1];
    const float* Wenc  = (const float*)d_in[2];
    const float* benc  = (const float*)d_in[3];
    const float* genc  = (const float*)d_in[4];
    const float* beenc = (const float*)d_in[5];
    const float* Wdec  = (const float*)d_in[6];
    const float* bdec  = (const float*)d_in[7];
    const float* gdec  = (const float*)d_in[8];
    const float* bedec = (const float*)d_in[9];
    const float* Wout  = (const float*)d_in[10];
    const float* bout  = (const float*)d_in[11];
    float* out = (float*)d_out;

    if (ws_size < WS_NEEDED) return;

    char* ws = (char*)d_ws;
    u16* joint  = (u16*)(ws + O_JOINT);
    u16* wout_b = (u16*)(ws + O_WOUT);
    u16* encln  = (u16*)(ws + O_ENCLN);
    u16* decln  = (u16*)(ws + O_DECLN);
    u16* encin  = (u16*)(ws + O_ENCIN);
    u16* decin  = (u16*)(ws + O_DECIN);
    u16* wenc_b = (u16*)(ws + O_WENC);
    u16* wdec_b = (u16*)(ws + O_WDEC);
    float* eproj = (float*)(ws + O_EPROJ);
    float* dproj = (float*)(ws + O_DPROJ);

    // 1) bf16 converts
    cvt_bf16<<<1024, 256, 0, stream>>>(enc,  encin,  (T_ * B_ * EENC) / 4);
    cvt_bf16<<<160,  256, 0, stream>>>(dec,  decin,  (U_ * B_ * EDEC) / 4);
    cvt_bf16<<<640,  256, 0, stream>>>(Wenc, wenc_b, (J_ * EENC) / 4);
    cvt_bf16<<<400,  256, 0, stream>>>(Wdec, wdec_b, (J_ * EDEC) / 4);
    cvt_bf16<<<2560, 256, 0, stream>>>(Wout, wout_b, (V_ * J_) / 4);

    // 2) stage-1 projections (bias folded into LN)
    gemm_bt<<<dim3(J_ / 128, (T_ * B_) / 128), 256, 0, stream>>>(encin, wenc_b, eproj, nullptr, EENC, J_);
    gemm_bt<<<dim3(J_ / 128, (U_ * B_) / 128), 256, 0, stream>>>(decin, wdec_b, dproj, nullptr, EDEC, J_);

    // 3) LayerNorm (+bias +affine), transpose to [B, T/U, J], bf16
    ln_kernel<<<T_ * B_, 256, 0, stream>>>(eproj, benc, genc, beenc, encln, B_, T_);
    ln_kernel<<<U_ * B_, 256, 0, stream>>>(dproj, bdec, gdec, bedec, decln, B_, U_);

    // 4) joint = relu(enc + dec) materialized bf16 [B*T*U][J]
    joint_mat<<<(B_ * T_ * U_ * (J_ / 8)) / 256, 256, 0, stream>>>(encln, decln, joint);

    // 5) vocab projection: [65536, 640] x [640, 4096]^T + b_out -> d_out
    gemm_big<<<(B_ * T_ * U_ / 128) * (V_ / 128), 256, 0, stream>>>(joint, wout_b, out, bout);
}

// Round 16
// 515.335 us; speedup vs baseline: 5.3291x; 5.3291x over previous
//
#include <hip/hip_runtime.h>
#include <stdint.h>

// Problem constants
#define T_    256
#define B_    4
#define U_    64
#define EENC  1024
#define EDEC  640
#define J_    640
#define V_    4096

typedef unsigned short u16;
typedef unsigned int   u32;
typedef __bf16 bf16x8 __attribute__((ext_vector_type(8)));
typedef short  s16x8  __attribute__((ext_vector_type(8)));
typedef float  f32x4  __attribute__((ext_vector_type(4)));

__device__ __forceinline__ u16 f2bf(float f) {
    u32 u = __builtin_bit_cast(u32, f);
    u = (u + 0x7FFFu + ((u >> 16) & 1u)) >> 16;
    return (u16)u;
}
__device__ __forceinline__ float bf2f(u16 b) {
    return __builtin_bit_cast(float, (u32)b << 16);
}

// ---------------- f32 -> bf16 convert (vectorized x4) ----------------
__global__ __launch_bounds__(256) void cvt_bf16(const float* __restrict__ src,
                                                u16* __restrict__ dst, int n4) {
    int i = blockIdx.x * 256 + threadIdx.x;
    if (i < n4) {
        float4 v = reinterpret_cast<const float4*>(src)[i];
        ushort4 o;
        o.x = f2bf(v.x); o.y = f2bf(v.y); o.z = f2bf(v.z); o.w = f2bf(v.w);
        reinterpret_cast<ushort4*>(dst)[i] = o;
    }
}

// ---------------- LayerNorm over J=640 + bias + affine, bf16 out, transposed ----------------
__global__ __launch_bounds__(256) void ln_kernel(const float* __restrict__ proj,
                                                 const float* __restrict__ bias,
                                                 const float* __restrict__ gamma,
                                                 const float* __restrict__ beta,
                                                 u16* __restrict__ out,
                                                 int BDIM, int OUTER) {
    int pr = blockIdx.x;
    int b = pr % BDIM, outer = pr / BDIM;
    const float* row = proj + (size_t)pr * J_;
    int tid = threadIdx.x;

    float x0 = row[tid] + bias[tid];
    float x1 = row[tid + 256] + bias[tid + 256];
    float x2 = 0.f;
    bool has3 = (tid < J_ - 512);
    if (has3) x2 = row[tid + 512] + bias[tid + 512];

    float s1 = x0 + x1 + x2;
    float s2 = x0 * x0 + x1 * x1 + x2 * x2;
    for (int off = 32; off; off >>= 1) {
        s1 += __shfl_down(s1, off, 64);
        s2 += __shfl_down(s2, off, 64);
    }
    __shared__ float ws1[4], ws2[4];
    int w = tid >> 6, lane = tid & 63;
    if (lane == 0) { ws1[w] = s1; ws2[w] = s2; }
    __syncthreads();
    float S1 = ws1[0] + ws1[1] + ws1[2] + ws1[3];
    float S2 = ws2[0] + ws2[1] + ws2[2] + ws2[3];
    float mu = S1 * (1.f / J_);
    float var = S2 * (1.f / J_) - mu * mu;
    float inv = 1.0f / sqrtf(var + 1e-5f);

    size_t orow = ((size_t)b * OUTER + outer) * J_;
    out[orow + tid]       = f2bf((x0 - mu) * inv * gamma[tid]       + beta[tid]);
    out[orow + tid + 256] = f2bf((x1 - mu) * inv * gamma[tid + 256] + beta[tid + 256]);
    if (has3)
        out[orow + tid + 512] = f2bf((x2 - mu) * inv * gamma[tid + 512] + beta[tid + 512]);
}

// ---------------- joint materialization: relu(enc[b,t,:] + dec[b,u,:]) -> bf16 [B*T*U][J] ----------------
__global__ __launch_bounds__(256) void joint_mat(const u16* __restrict__ encln,
                                                 const u16* __restrict__ decln,
                                                 u16* __restrict__ joint) {
    int g = blockIdx.x * 256 + threadIdx.x;
    int row = g / (J_ / 8);
    int jc = g - row * (J_ / 8);
    int b = row >> 14;
    int t = (row >> 6) & (T_ - 1);
    int u = row & (U_ - 1);
    s16x8 e = *reinterpret_cast<const s16x8*>(encln + ((size_t)(b * T_ + t)) * J_ + jc * 8);
    s16x8 d = *reinterpret_cast<const s16x8*>(decln + ((size_t)(b * U_ + u)) * J_ + jc * 8);
    s16x8 o;
#pragma unroll
    for (int k = 0; k < 8; ++k) {
        float v = bf2f((u16)e[k]) + bf2f((u16)d[k]);
        o[k] = (short)f2bf(fmaxf(v, 0.f));
    }
    *reinterpret_cast<s16x8*>(joint + (size_t)row * J_ + jc * 8) = o;
}

// ---------------- m97-structure 128x128 GEMM (stage-1 projections) ----------------
__global__ __launch_bounds__(256) void gemm_bt(const u16* __restrict__ A,
                                               const u16* __restrict__ Bt,
                                               float* __restrict__ C,
                                               const float* __restrict__ bias,
                                               int K, int ldc) {
    __shared__ u16 As[128 * 64];
    __shared__ u16 Bs[128 * 64];
    const int tid = threadIdx.x;
    const int w = tid >> 6, lane = tid & 63;
    const int wr = w >> 1, wc = w & 1;
    const size_t m0 = (size_t)blockIdx.y * 128;
    const size_t n0 = (size_t)blockIdx.x * 128;

    f32x4 acc[4][4] = {};

    const int l3 = lane >> 3;
    const int c8 = (lane & 7) * 8;
    const int nkt = K >> 6;

    for (int kt = 0; kt < nkt; ++kt) {
        if (kt) __syncthreads();
        const int k0 = kt << 6;
#pragma unroll
        for (int i = 0; i < 4; ++i) {
            const int c = w * 4 + i;
            const int r = c * 8 + l3;
            const u16* ga = A  + (m0 + r) * (size_t)K + k0 + c8;
            const u16* gb = Bt + (n0 + r) * (size_t)K + k0 + c8;
            __builtin_amdgcn_global_load_lds(
                (const __attribute__((address_space(1))) void*)ga,
                (__attribute__((address_space(3))) void*)(As + c * 512), 16, 0, 0);
            __builtin_amdgcn_global_load_lds(
                (const __attribute__((address_space(1))) void*)gb,
                (__attribute__((address_space(3))) void*)(Bs + c * 512), 16, 0, 0);
        }
        __syncthreads();

#pragma unroll
        for (int kk = 0; kk < 2; ++kk) {
            bf16x8 af[4], bfr[4];
#pragma unroll
            for (int i = 0; i < 4; ++i) {
                int ra = wr * 64 + i * 16 + (lane & 15);
                af[i] = *reinterpret_cast<const bf16x8*>(As + ra * 64 + kk * 32 + (lane >> 4) * 8);
                int rb = wc * 64 + i * 16 + (lane & 15);
                bfr[i] = *reinterpret_cast<const bf16x8*>(Bs + rb * 64 + kk * 32 + (lane >> 4) * 8);
            }
#pragma unroll
            for (int i = 0; i < 4; ++i)
#pragma unroll
                for (int j = 0; j < 4; ++j)
                    acc[i][j] = __builtin_amdgcn_mfma_f32_16x16x32_bf16(af[i], bfr[j], acc[i][j], 0, 0, 0);
        }
    }

    const int r4 = (lane >> 4) * 4;
    const int cl = lane & 15;
#pragma unroll
    for (int i = 0; i < 4; ++i) {
#pragma unroll
        for (int j = 0; j < 4; ++j) {
            size_t grow = m0 + wr * 64 + i * 16 + r4;
            size_t gcol = n0 + wc * 64 + j * 16 + cl;
            float bv = bias ? bias[gcol] : 0.f;
#pragma unroll
            for (int r = 0; r < 4; ++r)
                C[(grow + r) * (size_t)ldc + gcol] = acc[i][j][r] + bv;
        }
    }
}

// ---------------- vocab projection: 128x128 tile, BK=32, 4 wgs/CU ----------------
// R16 = R15's concurrency experiment with the CORRECT epilogue (R15's bounce
// pattern was 8-way-conflicted reads + 16B-fragment nt stores: 4.6e7 conflicts,
// 3.3x write amplification, 2746us). Epilogue now = R9's verified pattern:
// bounce [64][132] f32; write phase 2-way conflicts; read phase 2 rows x 512B
// CONTIGUOUS per instruction; nt f32x4 stores of 512B chunks.
// 256 thr (4 waves 2x2), dbuf LDS 32 KB + bounce overlay 33 KB -> 4 wgs/CU:
// 4 independent barrier domains interleave staging/MFMA/epilogue bursts.
#define BKS  32
#define BIGK 640
#define BIGN 4096
#define NTS  (BIGK / BKS)

__global__ __launch_bounds__(256, 4) void gemm_big(const u16* __restrict__ A,
                                                   const u16* __restrict__ Bt,
                                                   float* __restrict__ C,
                                                   const float* __restrict__ bias) {
    __shared__ u16 shm[16896];   // 33792 B: staging dbuf 2x8192 u16; bounce 64x132 f32 overlays

    const int tid = threadIdx.x;
    const int w = tid >> 6, lane = tid & 63;
    const int wr = w >> 1, wc = w & 1;
    const int fr = lane & 15, fq = lane >> 4;

    // n-ownership: xcd = lin&7 owns n-tiles {4*xcd..4*xcd+3}; n innermost so
    // 4 consecutive wgs share one A-tile (L2-hot after first fetch).
    const int lin = blockIdx.x;
    const int xcd = lin & 7;
    const int idx = lin >> 3;            // 0..2047
    const size_t m0 = (size_t)(idx >> 2) * 128;
    const size_t n0 = (size_t)(xcd * 4 + (idx & 3)) * 128;

    // staging: thread -> row = c*64 + (tid>>2), phys seg = tid&3 (16B units).
    // T2 involution: source seg = phys ^ (row&3); (c*64+srow)&3 == srow&3.
    const int srow = tid >> 2;                 // 0..63
    const int sseg = (tid & 3) ^ (srow & 3);
    const u16* aga = A  + (m0 + srow) * (size_t)BIGK + sseg * 8;
    const u16* bga = Bt + (n0 + srow) * (size_t)BIGK + sseg * 8;

    f32x4 acc[4][4] = {};

    // buf bo: A at bo*8192, B at bo*8192+4096; call c (64 rows) adds c*2048.
#define STAGE(bo, k0)                                                              \
    { _Pragma("unroll")                                                            \
      for (int c = 0; c < 2; ++c) {                                                \
        __builtin_amdgcn_global_load_lds(                                          \
            (const __attribute__((address_space(1))) void*)(aga + (size_t)c * 64 * BIGK + (k0)), \
            (__attribute__((address_space(3))) void*)(&shm[(bo) * 8192 + c * 2048 + tid * 8]), 16, 0, 0); \
        __builtin_amdgcn_global_load_lds(                                          \
            (const __attribute__((address_space(1))) void*)(bga + (size_t)c * 64 * BIGK + (k0)), \
            (__attribute__((address_space(3))) void*)(&shm[(bo) * 8192 + 4096 + c * 2048 + tid * 8]), 16, 0, 0); \
      } }

    // ds_read: logical (row, colbyte=fq*16) -> physical colbyte ^ ((row&3)<<4)
#define RD_A(bo, mi)                                                               \
    (*reinterpret_cast<const bf16x8*>(&shm[(bo) * 8192 +                           \
        (wr * 64 + (mi) * 16 + fr) * BKS +                                         \
        (((fq * 16) ^ (((wr * 64 + (mi) * 16 + fr) & 3) << 4)) >> 1)]))
#define RD_B(bo, ni)                                                               \
    (*reinterpret_cast<const bf16x8*>(&shm[(bo) * 8192 + 4096 +                    \
        (wc * 64 + (ni) * 16 + fr) * BKS +                                         \
        (((fq * 16) ^ (((wc * 64 + (ni) * 16 + fr) & 3) << 4)) >> 1)]))

#define VM0   asm volatile("s_waitcnt vmcnt(0)" ::: "memory")
#define LGKM0 asm volatile("s_waitcnt lgkmcnt(0)" ::: "memory")

    // prologue
    STAGE(0, 0);
    VM0;
    __builtin_amdgcn_s_barrier();

    for (int t = 0; t < NTS; ++t) {
        const int cur = t & 1;
        const bool pf = (t + 1 < NTS);
        bf16x8 af[4], bf[4];

#pragma unroll
        for (int i = 0; i < 4; ++i) af[i] = RD_A(cur, i);
#pragma unroll
        for (int j = 0; j < 4; ++j) bf[j] = RD_B(cur, j);
        if (pf) STAGE(cur ^ 1, (t + 1) * BKS);
        LGKM0;
        __builtin_amdgcn_s_setprio(1);
#pragma unroll
        for (int i = 0; i < 4; ++i)
#pragma unroll
            for (int j = 0; j < 4; ++j)
                acc[i][j] = __builtin_amdgcn_mfma_f32_16x16x32_bf16(af[i], bf[j], acc[i][j], 0, 0, 0);
        __builtin_amdgcn_s_setprio(0);
        if (pf) {
            VM0;
            __builtin_amdgcn_s_barrier();
        }
    }

#undef STAGE
#undef RD_A
#undef RD_B
#undef VM0
#undef LGKM0

    // ---- epilogue: LDS bounce -> contiguous f32x4 nt stores (R9 pattern) ----
    // write: waves wr==half deposit their 64x128 quadrant, stride 132 (2-way max).
    // read/store: each wave handles 16 rows; per instruction lane (l>>5) picks
    // row pair, (l&31)*4 cols -> 2 x 512B contiguous chunks.
    float* bnc = reinterpret_cast<float*>(shm);
#pragma unroll
    for (int half = 0; half < 2; ++half) {
        __syncthreads();
        if (wr == half) {
#pragma unroll
            for (int ni = 0; ni < 4; ++ni) {
                const int col = wc * 64 + ni * 16 + fr;
                const float bv = bias[n0 + col];
#pragma unroll
                for (int mi = 0; mi < 4; ++mi) {
                    const int lr = mi * 16 + fq * 4;
#pragma unroll
                    for (int r = 0; r < 4; ++r)
                        bnc[(lr + r) * 132 + col] = acc[mi][ni][r] + bv;
                }
            }
        }
        __syncthreads();
#pragma unroll
        for (int rr = 0; rr < 8; ++rr) {
            const int lrow = w * 16 + rr * 2 + (lane >> 5);
            const size_t grow = m0 + half * 64 + lrow;
            f32x4 v = *reinterpret_cast<const f32x4*>(&bnc[lrow * 132 + (lane & 31) * 4]);
            __builtin_nontemporal_store(v,
                reinterpret_cast<f32x4*>(&C[grow * (size_t)BIGN + n0 + (lane & 31) * 4]));
        }
    }
}

// ---------------- workspace layout (bytes) ----------------
static const size_t O_JOINT = 0;                              // bf16 [65536][640]
static const size_t O_WOUT  = 83886080;                       // bf16 [4096][640]
static const size_t O_ENCLN = 89128960;                       // bf16 [B*T][J]
static const size_t O_DECLN = 90439680;                       // bf16 [B*U][J]
static const size_t O_ENCIN = 90767360;                       // bf16 [T*B][EENC]
static const size_t O_DECIN = 92864512;                       // bf16 [U*B][EDEC]
static const size_t O_WENC  = 93192192;                       // bf16 [J][EENC]
static const size_t O_WDEC  = 94502912;                       // bf16 [J][EDEC]
static const size_t O_EPROJ = 95322112;                       // f32  [T*B][J]
static const size_t O_DPROJ = 97943552;                       // f32  [U*B][J]
static const size_t WS_NEEDED = 98598912;

extern "C" void kernel_launch(void* const* d_in, const int* in_sizes, int n_in,
                              void* d_out, int out_size, void* d_ws, size_t ws_size,
                              hipStream_t stream) {
    const float* enc   = (const float*)d_in[0];
    const float* dec   = (const float*)d_in[1];
    const float* Wenc  = (const float*)d_in[2];
    const float* benc  = (const float*)d_in[3];
    const float* genc  = (const float*)d_in[4];
    const float* beenc = (const float*)d_in[5];
    const float* Wdec  = (const float*)d_in[6];
    const float* bdec  = (const float*)d_in[7];
    const float* gdec  = (const float*)d_in[8];
    const float* bedec = (const float*)d_in[9];
    const float* Wout  = (const float*)d_in[10];
    const float* bout  = (const float*)d_in[11];
    float* out = (float*)d_out;

    if (ws_size < WS_NEEDED) return;

    char* ws = (char*)d_ws;
    u16* joint  = (u16*)(ws + O_JOINT);
    u16* wout_b = (u16*)(ws + O_WOUT);
    u16* encln  = (u16*)(ws + O_ENCLN);
    u16* decln  = (u16*)(ws + O_DECLN);
    u16* encin  = (u16*)(ws + O_ENCIN);
    u16* decin  = (u16*)(ws + O_DECIN);
    u16* wenc_b = (u16*)(ws + O_WENC);
    u16* wdec_b = (u16*)(ws + O_WDEC);
    float* eproj = (float*)(ws + O_EPROJ);
    float* dproj = (float*)(ws + O_DPROJ);

    // 1) bf16 converts
    cvt_bf16<<<1024, 256, 0, stream>>>(enc,  encin,  (T_ * B_ * EENC) / 4);
    cvt_bf16<<<160,  256, 0, stream>>>(dec,  decin,  (U_ * B_ * EDEC) / 4);
    cvt_bf16<<<640,  256, 0, stream>>>(Wenc, wenc_b, (J_ * EENC) / 4);
    cvt_bf16<<<400,  256, 0, stream>>>(Wdec, wdec_b, (J_ * EDEC) / 4);
    cvt_bf16<<<2560, 256, 0, stream>>>(Wout, wout_b, (V_ * J_) / 4);

    // 2) stage-1 projections (bias folded into LN)
    gemm_bt<<<dim3(J_ / 128, (T_ * B_) / 128), 256, 0, stream>>>(encin, wenc_b, eproj, nullptr, EENC, J_);
    gemm_bt<<<dim3(J_ / 128, (U_ * B_) / 128), 256, 0, stream>>>(decin, wdec_b, dproj, nullptr, EDEC, J_);

    // 3) LayerNorm (+bias +affine), transpose to [B, T/U, J], bf16
    ln_kernel<<<T_ * B_, 256, 0, stream>>>(eproj, benc, genc, beenc, encln, B_, T_);
    ln_kernel<<<U_ * B_, 256, 0, stream>>>(dproj, bdec, gdec, bedec, decln, B_, U_);

    // 4) joint = relu(enc + dec) materialized bf16 [B*T*U][J]
    joint_mat<<<(B_ * T_ * U_ * (J_ / 8)) / 256, 256, 0, stream>>>(encln, decln, joint);

    // 5) vocab projection: [65536, 640] x [640, 4096]^T + b_out -> d_out
    gemm_big<<<(B_ * T_ * U_ / 128) * (V_ / 128), 256, 0, stream>>>(joint, wout_b, out, bout);
}

// Round 17
// 497.611 us; speedup vs baseline: 5.5189x; 1.0356x over previous
//
#include <hip/hip_runtime.h>
#include <stdint.h>

// Problem constants
#define T_    256
#define B_    4
#define U_    64
#define EENC  1024
#define EDEC  640
#define J_    640
#define V_    4096

typedef unsigned short u16;
typedef unsigned int   u32;
typedef __bf16 bf16x8 __attribute__((ext_vector_type(8)));
typedef short  s16x8  __attribute__((ext_vector_type(8)));
typedef float  f32x4  __attribute__((ext_vector_type(4)));

__device__ __forceinline__ u16 f2bf(float f) {
    u32 u = __builtin_bit_cast(u32, f);
    u = (u + 0x7FFFu + ((u >> 16) & 1u)) >> 16;
    return (u16)u;
}
__device__ __forceinline__ float bf2f(u16 b) {
    return __builtin_bit_cast(float, (u32)b << 16);
}

// ---------------- f32 -> bf16 convert (vectorized x4) ----------------
__global__ __launch_bounds__(256) void cvt_bf16(const float* __restrict__ src,
                                                u16* __restrict__ dst, int n4) {
    int i = blockIdx.x * 256 + threadIdx.x;
    if (i < n4) {
        float4 v = reinterpret_cast<const float4*>(src)[i];
        ushort4 o;
        o.x = f2bf(v.x); o.y = f2bf(v.y); o.z = f2bf(v.z); o.w = f2bf(v.w);
        reinterpret_cast<ushort4*>(dst)[i] = o;
    }
}

// ---------------- LayerNorm over J=640 + bias + affine, bf16 out, transposed ----------------
__global__ __launch_bounds__(256) void ln_kernel(const float* __restrict__ proj,
                                                 const float* __restrict__ bias,
                                                 const float* __restrict__ gamma,
                                                 const float* __restrict__ beta,
                                                 u16* __restrict__ out,
                                                 int BDIM, int OUTER) {
    int pr = blockIdx.x;
    int b = pr % BDIM, outer = pr / BDIM;
    const float* row = proj + (size_t)pr * J_;
    int tid = threadIdx.x;

    float x0 = row[tid] + bias[tid];
    float x1 = row[tid + 256] + bias[tid + 256];
    float x2 = 0.f;
    bool has3 = (tid < J_ - 512);
    if (has3) x2 = row[tid + 512] + bias[tid + 512];

    float s1 = x0 + x1 + x2;
    float s2 = x0 * x0 + x1 * x1 + x2 * x2;
    for (int off = 32; off; off >>= 1) {
        s1 += __shfl_down(s1, off, 64);
        s2 += __shfl_down(s2, off, 64);
    }
    __shared__ float ws1[4], ws2[4];
    int w = tid >> 6, lane = tid & 63;
    if (lane == 0) { ws1[w] = s1; ws2[w] = s2; }
    __syncthreads();
    float S1 = ws1[0] + ws1[1] + ws1[2] + ws1[3];
    float S2 = ws2[0] + ws2[1] + ws2[2] + ws2[3];
    float mu = S1 * (1.f / J_);
    float var = S2 * (1.f / J_) - mu * mu;
    float inv = 1.0f / sqrtf(var + 1e-5f);

    size_t orow = ((size_t)b * OUTER + outer) * J_;
    out[orow + tid]       = f2bf((x0 - mu) * inv * gamma[tid]       + beta[tid]);
    out[orow + tid + 256] = f2bf((x1 - mu) * inv * gamma[tid + 256] + beta[tid + 256]);
    if (has3)
        out[orow + tid + 512] = f2bf((x2 - mu) * inv * gamma[tid + 512] + beta[tid + 512]);
}

// ---------------- joint materialization: relu(enc[b,t,:] + dec[b,u,:]) -> bf16 [B*T*U][J] ----------------
__global__ __launch_bounds__(256) void joint_mat(const u16* __restrict__ encln,
                                                 const u16* __restrict__ decln,
                                                 u16* __restrict__ joint) {
    int g = blockIdx.x * 256 + threadIdx.x;
    int row = g / (J_ / 8);
    int jc = g - row * (J_ / 8);
    int b = row >> 14;
    int t = (row >> 6) & (T_ - 1);
    int u = row & (U_ - 1);
    s16x8 e = *reinterpret_cast<const s16x8*>(encln + ((size_t)(b * T_ + t)) * J_ + jc * 8);
    s16x8 d = *reinterpret_cast<const s16x8*>(decln + ((size_t)(b * U_ + u)) * J_ + jc * 8);
    s16x8 o;
#pragma unroll
    for (int k = 0; k < 8; ++k) {
        float v = bf2f((u16)e[k]) + bf2f((u16)d[k]);
        o[k] = (short)f2bf(fmaxf(v, 0.f));
    }
    *reinterpret_cast<s16x8*>(joint + (size_t)row * J_ + jc * 8) = o;
}

// ---------------- m97-structure 128x128 GEMM (stage-1 projections) ----------------
__global__ __launch_bounds__(256) void gemm_bt(const u16* __restrict__ A,
                                               const u16* __restrict__ Bt,
                                               float* __restrict__ C,
                                               const float* __restrict__ bias,
                                               int K, int ldc) {
    __shared__ u16 As[128 * 64];
    __shared__ u16 Bs[128 * 64];
    const int tid = threadIdx.x;
    const int w = tid >> 6, lane = tid & 63;
    const int wr = w >> 1, wc = w & 1;
    const size_t m0 = (size_t)blockIdx.y * 128;
    const size_t n0 = (size_t)blockIdx.x * 128;

    f32x4 acc[4][4] = {};

    const int l3 = lane >> 3;
    const int c8 = (lane & 7) * 8;
    const int nkt = K >> 6;

    for (int kt = 0; kt < nkt; ++kt) {
        if (kt) __syncthreads();
        const int k0 = kt << 6;
#pragma unroll
        for (int i = 0; i < 4; ++i) {
            const int c = w * 4 + i;
            const int r = c * 8 + l3;
            const u16* ga = A  + (m0 + r) * (size_t)K + k0 + c8;
            const u16* gb = Bt + (n0 + r) * (size_t)K + k0 + c8;
            __builtin_amdgcn_global_load_lds(
                (const __attribute__((address_space(1))) void*)ga,
                (__attribute__((address_space(3))) void*)(As + c * 512), 16, 0, 0);
            __builtin_amdgcn_global_load_lds(
                (const __attribute__((address_space(1))) void*)gb,
                (__attribute__((address_space(3))) void*)(Bs + c * 512), 16, 0, 0);
        }
        __syncthreads();

#pragma unroll
        for (int kk = 0; kk < 2; ++kk) {
            bf16x8 af[4], bfr[4];
#pragma unroll
            for (int i = 0; i < 4; ++i) {
                int ra = wr * 64 + i * 16 + (lane & 15);
                af[i] = *reinterpret_cast<const bf16x8*>(As + ra * 64 + kk * 32 + (lane >> 4) * 8);
                int rb = wc * 64 + i * 16 + (lane & 15);
                bfr[i] = *reinterpret_cast<const bf16x8*>(Bs + rb * 64 + kk * 32 + (lane >> 4) * 8);
            }
#pragma unroll
            for (int i = 0; i < 4; ++i)
#pragma unroll
                for (int j = 0; j < 4; ++j)
                    acc[i][j] = __builtin_amdgcn_mfma_f32_16x16x32_bf16(af[i], bfr[j], acc[i][j], 0, 0, 0);
        }
    }

    const int r4 = (lane >> 4) * 4;
    const int cl = lane & 15;
#pragma unroll
    for (int i = 0; i < 4; ++i) {
#pragma unroll
        for (int j = 0; j < 4; ++j) {
            size_t grow = m0 + wr * 64 + i * 16 + r4;
            size_t gcol = n0 + wc * 64 + j * 16 + cl;
            float bv = bias ? bias[gcol] : 0.f;
#pragma unroll
            for (int r = 0; r < 4; ++r)
                C[(grow + r) * (size_t)ldc + gcol] = acc[i][j][r] + bv;
        }
    }
}

// ---------------- vocab projection: 128x256 tile, BK=32, triple-buffered (R9 best) ----------------
// Final configuration after the full experiment matrix (R2..R16):
// - triple-buffered LDS ring, counted vmcnt(3) (never drain-to-0 mid-loop)
// - T2 involution swizzle (linear gload_lds dest + pre-swizzled source + same
//   XOR on ds_read)
// - n-ownership grid: xcd owns 2 n-tiles (B panel L2-hot; A-pair wgs adjacent)
// - 2 wgs/CU (LDS 72 KiB): epilogue drain overlaps co-resident wg's K-loop
// - epilogue: LDS bounce -> contiguous f32x4 nt stores (full 128B HBM lines;
//   cached stores wash L2/LLC (+80-106us); scalar nt amplifies writes 1.73x)
#define BKS  32
#define BIGK 640
#define BIGN 4096
#define NTS  (BIGK / BKS)
#define ASZ  (128 * BKS)   // u16 per A buffer
#define BSZ  (256 * BKS)   // u16 per B buffer

__global__ __launch_bounds__(512, 4) void gemm_big(const u16* __restrict__ A,
                                                   const u16* __restrict__ Bt,
                                                   float* __restrict__ C,
                                                   const float* __restrict__ bias) {
    __shared__ u16 shm[3 * ASZ + 3 * BSZ];   // 72 KiB (staging ring + epilogue bounce)

    const int tid = threadIdx.x;
    const int w = tid >> 6, lane = tid & 63;
    const int wr = w >> 2, wc = w & 3;
    const int fr = lane & 15, fq = lane >> 4;

    // XCD n-ownership: xcd = lin&7 owns n-tiles {2*xcd, 2*xcd+1}
    const int lin = blockIdx.x;
    const int xcd = lin & 7;
    const int idx = lin >> 3;            // 0..1023
    const size_t m0 = (size_t)(idx >> 1) * 128;
    const size_t n0 = (size_t)(xcd * 2 + (idx & 1)) * 256;

    // staging: thread tid covers LDS bytes [tid*16, tid*16+16) of each region
    // -> (row = tid>>2, phys seg = tid&3). T2 involution: source seg = phys ^ (row&3).
    const int arow = tid >> 2;                 // 0..127
    const int aseg = (tid & 3) ^ (arow & 3);
    const u16* aga  = A + (m0 + arow) * (size_t)BIGK + aseg * 8;
    const u16* bga0 = Bt + (n0 + arow) * (size_t)BIGK + aseg * 8;
    const u16* bga1 = bga0 + (size_t)128 * BIGK;
    const int sdst = w * 512;                  // u16: wave stripe in region

    f32x4 acc[4][4] = {};

#define STAGE(bo, k0)                                                              \
    { __builtin_amdgcn_global_load_lds(                                            \
          (const __attribute__((address_space(1))) void*)(aga + (k0)),             \
          (__attribute__((address_space(3))) void*)(&shm[(bo) * ASZ + sdst]), 16, 0, 0); \
      __builtin_amdgcn_global_load_lds(                                            \
          (const __attribute__((address_space(1))) void*)(bga0 + (k0)),            \
          (__attribute__((address_space(3))) void*)(&shm[3 * ASZ + (bo) * BSZ + sdst]), 16, 0, 0); \
      __builtin_amdgcn_global_load_lds(                                            \
          (const __attribute__((address_space(1))) void*)(bga1 + (k0)),            \
          (__attribute__((address_space(3))) void*)(&shm[3 * ASZ + (bo) * BSZ + 4096 + sdst]), 16, 0, 0); }

    // ds_read: logical (row, colbyte=fq*16) -> physical colbyte ^ ((row&3)<<4)
#define RD_A(bo, mi)                                                               \
    (*reinterpret_cast<const bf16x8*>(&shm[(bo) * ASZ +                            \
        (wr * 64 + (mi) * 16 + fr) * BKS +                                         \
        (((fq * 16) ^ (((wr * 64 + (mi) * 16 + fr) & 3) << 4)) >> 1)]))
#define RD_B(bo, ni)                                                               \
    (*reinterpret_cast<const bf16x8*>(&shm[3 * ASZ + (bo) * BSZ +                  \
        (wc * 64 + (ni) * 16 + fr) * BKS +                                         \
        (((fq * 16) ^ (((wc * 64 + (ni) * 16 + fr) & 3) << 4)) >> 1)]))

#define VM3   asm volatile("s_waitcnt vmcnt(3)" ::: "memory")
#define VM0   asm volatile("s_waitcnt vmcnt(0)" ::: "memory")
#define LGKM0 asm volatile("s_waitcnt lgkmcnt(0)" ::: "memory")

    // prologue: stage sets 0 and 1; wait for set 0 only (set 1 stays in flight)
    STAGE(0, 0);
    STAGE(1, BKS);
    VM3;
    __builtin_amdgcn_s_barrier();

    int cur = 0;
    for (int t = 0; t < NTS; ++t) {
        const bool pf2 = (t + 2 < NTS);
        int nx2 = cur + 2; if (nx2 >= 3) nx2 -= 3;
        bf16x8 af[4], bf[4];

#pragma unroll
        for (int i = 0; i < 4; ++i) af[i] = RD_A(cur, i);
#pragma unroll
        for (int j = 0; j < 4; ++j) bf[j] = RD_B(cur, j);
        if (pf2) STAGE(nx2, (t + 2) * BKS);
        LGKM0;
        __builtin_amdgcn_s_setprio(1);
#pragma unroll
        for (int i = 0; i < 4; ++i)
#pragma unroll
            for (int j = 0; j < 4; ++j)
                acc[i][j] = __builtin_amdgcn_mfma_f32_16x16x32_bf16(af[i], bf[j], acc[i][j], 0, 0, 0);
        __builtin_amdgcn_s_setprio(0);
        if (t + 1 < NTS) {
            if (pf2) VM3; else VM0;        // drain set t+1; keep t+2 in flight
            __builtin_amdgcn_s_barrier();
        }
        ++cur; if (cur >= 3) cur = 0;
    }

#undef STAGE
#undef RD_A
#undef RD_B
#undef VM3
#undef VM0
#undef LGKM0

    // ---- epilogue: LDS bounce -> contiguous f32x4 nt stores ----
    // bounce buffer: [64][257] f32 (65.8 KB, overlays the staging ring).
    // phase half=0: waves with wr==0 write rows 0..63 of the tile; all waves
    // then store 8 rows each as 64-lane f32x4 (1 KB/inst). half=1: wr==1 rows.
    float* bnc = reinterpret_cast<float*>(shm);
#pragma unroll
    for (int half = 0; half < 2; ++half) {
        __syncthreads();                    // prior phase reads / K-loop LDS use done
        if (wr == half) {
#pragma unroll
            for (int ni = 0; ni < 4; ++ni) {
                const int col = wc * 64 + ni * 16 + fr;
                const float bv = bias[n0 + col];
#pragma unroll
                for (int mi = 0; mi < 4; ++mi) {
                    const int lr = mi * 16 + fq * 4;
#pragma unroll
                    for (int r = 0; r < 4; ++r)
                        bnc[(lr + r) * 257 + col] = acc[mi][ni][r] + bv;
                }
            }
        }
        __syncthreads();
#pragma unroll
        for (int rr = 0; rr < 8; ++rr) {
            const int lrow = w * 8 + rr;
            const size_t grow = m0 + half * 64 + lrow;
            f32x4 v = *reinterpret_cast<const f32x4*>(&bnc[lrow * 257 + lane * 4]);
            __builtin_nontemporal_store(v,
                reinterpret_cast<f32x4*>(&C[grow * (size_t)BIGN + n0 + lane * 4]));
        }
    }
}

// ---------------- workspace layout (bytes) ----------------
static const size_t O_JOINT = 0;                              // bf16 [65536][640]
static const size_t O_WOUT  = 83886080;                       // bf16 [4096][640]
static const size_t O_ENCLN = 89128960;                       // bf16 [B*T][J]
static const size_t O_DECLN = 90439680;                       // bf16 [B*U][J]
static const size_t O_ENCIN = 90767360;                       // bf16 [T*B][EENC]
static const size_t O_DECIN = 92864512;                       // bf16 [U*B][EDEC]
static const size_t O_WENC  = 93192192;                       // bf16 [J][EENC]
static const size_t O_WDEC  = 94502912;                       // bf16 [J][EDEC]
static const size_t O_EPROJ = 95322112;                       // f32  [T*B][J]
static const size_t O_DPROJ = 97943552;                       // f32  [U*B][J]
static const size_t WS_NEEDED = 98598912;

extern "C" void kernel_launch(void* const* d_in, const int* in_sizes, int n_in,
                              void* d_out, int out_size, void* d_ws, size_t ws_size,
                              hipStream_t stream) {
    const float* enc   = (const float*)d_in[0];
    const float* dec   = (const float*)d_in[1];
    const float* Wenc  = (const float*)d_in[2];
    const float* benc  = (const float*)d_in[3];
    const float* genc  = (const float*)d_in[4];
    const float* beenc = (const float*)d_in[5];
    const float* Wdec  = (const float*)d_in[6];
    const float* bdec  = (const float*)d_in[7];
    const float* gdec  = (const float*)d_in[8];
    const float* bedec = (const float*)d_in[9];
    const float* Wout  = (const float*)d_in[10];
    const float* bout  = (const float*)d_in[11];
    float* out = (float*)d_out;

    if (ws_size < WS_NEEDED) return;

    char* ws = (char*)d_ws;
    u16* joint  = (u16*)(ws + O_JOINT);
    u16* wout_b = (u16*)(ws + O_WOUT);
    u16* encln  = (u16*)(ws + O_ENCLN);
    u16* decln  = (u16*)(ws + O_DECLN);
    u16* encin  = (u16*)(ws + O_ENCIN);
    u16* decin  = (u16*)(ws + O_DECIN);
    u16* wenc_b = (u16*)(ws + O_WENC);
    u16* wdec_b = (u16*)(ws + O_WDEC);
    float* eproj = (float*)(ws + O_EPROJ);
    float* dproj = (float*)(ws + O_DPROJ);

    // 1) bf16 converts
    cvt_bf16<<<1024, 256, 0, stream>>>(enc,  encin,  (T_ * B_ * EENC) / 4);
    cvt_bf16<<<160,  256, 0, stream>>>(dec,  decin,  (U_ * B_ * EDEC) / 4);
    cvt_bf16<<<640,  256, 0, stream>>>(Wenc, wenc_b, (J_ * EENC) / 4);
    cvt_bf16<<<400,  256, 0, stream>>>(Wdec, wdec_b, (J_ * EDEC) / 4);
    cvt_bf16<<<2560, 256, 0, stream>>>(Wout, wout_b, (V_ * J_) / 4);

    // 2) stage-1 projections (bias folded into LN)
    gemm_bt<<<dim3(J_ / 128, (T_ * B_) / 128), 256, 0, stream>>>(encin, wenc_b, eproj, nullptr, EENC, J_);
    gemm_bt<<<dim3(J_ / 128, (U_ * B_) / 128), 256, 0, stream>>>(decin, wdec_b, dproj, nullptr, EDEC, J_);

    // 3) LayerNorm (+bias +affine), transpose to [B, T/U, J], bf16
    ln_kernel<<<T_ * B_, 256, 0, stream>>>(eproj, benc, genc, beenc, encln, B_, T_);
    ln_kernel<<<U_ * B_, 256, 0, stream>>>(dproj, bdec, gdec, bedec, decln, B_, U_);

    // 4) joint = relu(enc + dec) materialized bf16 [B*T*U][J]
    joint_mat<<<(B_ * T_ * U_ * (J_ / 8)) / 256, 256, 0, stream>>>(encln, decln, joint);

    // 5) vocab projection: [65536, 640] x [640, 4096]^T + b_out -> d_out
    gemm_big<<<(B_ * T_ * U_ / 128) * (V_ / 256), 512, 0, stream>>>(joint, wout_b, out, bout);
}

// Round 18
// 483.293 us; speedup vs baseline: 5.6824x; 1.0296x over previous
//
#include <hip/hip_runtime.h>
#include <stdint.h>

// Problem constants
#define T_    256
#define B_    4
#define U_    64
#define EENC  1024
#define EDEC  640
#define J_    640
#define V_    4096

typedef unsigned short u16;
typedef unsigned int   u32;
typedef __bf16 bf16x8 __attribute__((ext_vector_type(8)));
typedef short  s16x8  __attribute__((ext_vector_type(8)));
typedef float  f32x4  __attribute__((ext_vector_type(4)));

__device__ __forceinline__ u16 f2bf(float f) {
    u32 u = __builtin_bit_cast(u32, f);
    u = (u + 0x7FFFu + ((u >> 16) & 1u)) >> 16;
    return (u16)u;
}
__device__ __forceinline__ float bf2f(u16 b) {
    return __builtin_bit_cast(float, (u32)b << 16);
}

// ---------------- f32 -> bf16 convert (vectorized x4) ----------------
__global__ __launch_bounds__(256) void cvt_bf16(const float* __restrict__ src,
                                                u16* __restrict__ dst, int n4) {
    int i = blockIdx.x * 256 + threadIdx.x;
    if (i < n4) {
        float4 v = reinterpret_cast<const float4*>(src)[i];
        ushort4 o;
        o.x = f2bf(v.x); o.y = f2bf(v.y); o.z = f2bf(v.z); o.w = f2bf(v.w);
        reinterpret_cast<ushort4*>(dst)[i] = o;
    }
}

// ---------------- LayerNorm over J=640 + bias + affine, bf16 out, transposed ----------------
__global__ __launch_bounds__(256) void ln_kernel(const float* __restrict__ proj,
                                                 const float* __restrict__ bias,
                                                 const float* __restrict__ gamma,
                                                 const float* __restrict__ beta,
                                                 u16* __restrict__ out,
                                                 int BDIM, int OUTER) {
    int pr = blockIdx.x;
    int b = pr % BDIM, outer = pr / BDIM;
    const float* row = proj + (size_t)pr * J_;
    int tid = threadIdx.x;

    float x0 = row[tid] + bias[tid];
    float x1 = row[tid + 256] + bias[tid + 256];
    float x2 = 0.f;
    bool has3 = (tid < J_ - 512);
    if (has3) x2 = row[tid + 512] + bias[tid + 512];

    float s1 = x0 + x1 + x2;
    float s2 = x0 * x0 + x1 * x1 + x2 * x2;
    for (int off = 32; off; off >>= 1) {
        s1 += __shfl_down(s1, off, 64);
        s2 += __shfl_down(s2, off, 64);
    }
    __shared__ float ws1[4], ws2[4];
    int w = tid >> 6, lane = tid & 63;
    if (lane == 0) { ws1[w] = s1; ws2[w] = s2; }
    __syncthreads();
    float S1 = ws1[0] + ws1[1] + ws1[2] + ws1[3];
    float S2 = ws2[0] + ws2[1] + ws2[2] + ws2[3];
    float mu = S1 * (1.f / J_);
    float var = S2 * (1.f / J_) - mu * mu;
    float inv = 1.0f / sqrtf(var + 1e-5f);

    size_t orow = ((size_t)b * OUTER + outer) * J_;
    out[orow + tid]       = f2bf((x0 - mu) * inv * gamma[tid]       + beta[tid]);
    out[orow + tid + 256] = f2bf((x1 - mu) * inv * gamma[tid + 256] + beta[tid + 256]);
    if (has3)
        out[orow + tid + 512] = f2bf((x2 - mu) * inv * gamma[tid + 512] + beta[tid + 512]);
}

// ---------------- joint materialization: relu(enc[b,t,:] + dec[b,u,:]) -> bf16 [B*T*U][J] ----------------
__global__ __launch_bounds__(256) void joint_mat(const u16* __restrict__ encln,
                                                 const u16* __restrict__ decln,
                                                 u16* __restrict__ joint) {
    int g = blockIdx.x * 256 + threadIdx.x;
    int row = g / (J_ / 8);
    int jc = g - row * (J_ / 8);
    int b = row >> 14;
    int t = (row >> 6) & (T_ - 1);
    int u = row & (U_ - 1);
    s16x8 e = *reinterpret_cast<const s16x8*>(encln + ((size_t)(b * T_ + t)) * J_ + jc * 8);
    s16x8 d = *reinterpret_cast<const s16x8*>(decln + ((size_t)(b * U_ + u)) * J_ + jc * 8);
    s16x8 o;
#pragma unroll
    for (int k = 0; k < 8; ++k) {
        float v = bf2f((u16)e[k]) + bf2f((u16)d[k]);
        o[k] = (short)f2bf(fmaxf(v, 0.f));
    }
    *reinterpret_cast<s16x8*>(joint + (size_t)row * J_ + jc * 8) = o;
}

// ---------------- m97-structure 128x128 GEMM (stage-1 projections) ----------------
__global__ __launch_bounds__(256) void gemm_bt(const u16* __restrict__ A,
                                               const u16* __restrict__ Bt,
                                               float* __restrict__ C,
                                               const float* __restrict__ bias,
                                               int K, int ldc) {
    __shared__ u16 As[128 * 64];
    __shared__ u16 Bs[128 * 64];
    const int tid = threadIdx.x;
    const int w = tid >> 6, lane = tid & 63;
    const int wr = w >> 1, wc = w & 1;
    const size_t m0 = (size_t)blockIdx.y * 128;
    const size_t n0 = (size_t)blockIdx.x * 128;

    f32x4 acc[4][4] = {};

    const int l3 = lane >> 3;
    const int c8 = (lane & 7) * 8;
    const int nkt = K >> 6;

    for (int kt = 0; kt < nkt; ++kt) {
        if (kt) __syncthreads();
        const int k0 = kt << 6;
#pragma unroll
        for (int i = 0; i < 4; ++i) {
            const int c = w * 4 + i;
            const int r = c * 8 + l3;
            const u16* ga = A  + (m0 + r) * (size_t)K + k0 + c8;
            const u16* gb = Bt + (n0 + r) * (size_t)K + k0 + c8;
            __builtin_amdgcn_global_load_lds(
                (const __attribute__((address_space(1))) void*)ga,
                (__attribute__((address_space(3))) void*)(As + c * 512), 16, 0, 0);
            __builtin_amdgcn_global_load_lds(
                (const __attribute__((address_space(1))) void*)gb,
                (__attribute__((address_space(3))) void*)(Bs + c * 512), 16, 0, 0);
        }
        __syncthreads();

#pragma unroll
        for (int kk = 0; kk < 2; ++kk) {
            bf16x8 af[4], bfr[4];
#pragma unroll
            for (int i = 0; i < 4; ++i) {
                int ra = wr * 64 + i * 16 + (lane & 15);
                af[i] = *reinterpret_cast<const bf16x8*>(As + ra * 64 + kk * 32 + (lane >> 4) * 8);
                int rb = wc * 64 + i * 16 + (lane & 15);
                bfr[i] = *reinterpret_cast<const bf16x8*>(Bs + rb * 64 + kk * 32 + (lane >> 4) * 8);
            }
#pragma unroll
            for (int i = 0; i < 4; ++i)
#pragma unroll
                for (int j = 0; j < 4; ++j)
                    acc[i][j] = __builtin_amdgcn_mfma_f32_16x16x32_bf16(af[i], bfr[j], acc[i][j], 0, 0, 0);
        }
    }

    const int r4 = (lane >> 4) * 4;
    const int cl = lane & 15;
#pragma unroll
    for (int i = 0; i < 4; ++i) {
#pragma unroll
        for (int j = 0; j < 4; ++j) {
            size_t grow = m0 + wr * 64 + i * 16 + r4;
            size_t gcol = n0 + wc * 64 + j * 16 + cl;
            float bv = bias ? bias[gcol] : 0.f;
#pragma unroll
            for (int r = 0; r < 4; ++r)
                C[(grow + r) * (size_t)ldc + gcol] = acc[i][j][r] + bv;
        }
    }
}

// ---------------- vocab projection: 128x256 tile, BK=32, triple-buffered ----------------
// R18 = R17 with ONE change: grid split over m-halves. R17's grid had every XCD
// covering all 512 m-tiles (for its 2 n-tiles) -> each A-tile fetched from HBM
// by 8 XCDs (R13 counters: FETCH 461MB vs ~90MB logical; LLC washed by the 1GB
// write stream). Now xcd>>2 picks the m-half, xcd&3 picks 4 n-tiles: each XCD
// covers 256 m x 4 n (B slice 1.31MB L2-fit), A-tile touched by 4 XCDs (2x less
// HBM fetch), and the 4 n-wgs sharing an A-tile are consecutive (L2-hot).
#define BKS  32
#define BIGK 640
#define BIGN 4096
#define NTS  (BIGK / BKS)
#define ASZ  (128 * BKS)   // u16 per A buffer
#define BSZ  (256 * BKS)   // u16 per B buffer

__global__ __launch_bounds__(512, 4) void gemm_big(const u16* __restrict__ A,
                                                   const u16* __restrict__ Bt,
                                                   float* __restrict__ C,
                                                   const float* __restrict__ bias) {
    __shared__ u16 shm[3 * ASZ + 3 * BSZ];   // 72 KiB (staging ring + epilogue bounce)

    const int tid = threadIdx.x;
    const int w = tid >> 6, lane = tid & 63;
    const int wr = w >> 2, wc = w & 3;
    const int fr = lane & 15, fq = lane >> 4;

    // XCD grid: mhalf = xcd>>2 (m-tiles [mhalf*256, mhalf*256+256)),
    // nsub = xcd&3 (n-tiles {nsub*4 .. nsub*4+3}); idx&3 innermost -> 4
    // consecutive wgs share one A-tile on the same XCD.
    const int lin = blockIdx.x;
    const int xcd = lin & 7;
    const int idx = lin >> 3;            // 0..1023
    const size_t m0 = ((size_t)(xcd >> 2) * 256 + (idx >> 2)) * 128;
    const size_t n0 = ((size_t)(xcd & 3) * 4 + (idx & 3)) * 256;

    // staging: thread tid covers LDS bytes [tid*16, tid*16+16) of each region
    // -> (row = tid>>2, phys seg = tid&3). T2 involution: source seg = phys ^ (row&3).
    const int arow = tid >> 2;                 // 0..127
    const int aseg = (tid & 3) ^ (arow & 3);
    const u16* aga  = A + (m0 + arow) * (size_t)BIGK + aseg * 8;
    const u16* bga0 = Bt + (n0 + arow) * (size_t)BIGK + aseg * 8;
    const u16* bga1 = bga0 + (size_t)128 * BIGK;
    const int sdst = w * 512;                  // u16: wave stripe in region

    f32x4 acc[4][4] = {};

#define STAGE(bo, k0)                                                              \
    { __builtin_amdgcn_global_load_lds(                                            \
          (const __attribute__((address_space(1))) void*)(aga + (k0)),             \
          (__attribute__((address_space(3))) void*)(&shm[(bo) * ASZ + sdst]), 16, 0, 0); \
      __builtin_amdgcn_global_load_lds(                                            \
          (const __attribute__((address_space(1))) void*)(bga0 + (k0)),            \
          (__attribute__((address_space(3))) void*)(&shm[3 * ASZ + (bo) * BSZ + sdst]), 16, 0, 0); \
      __builtin_amdgcn_global_load_lds(                                            \
          (const __attribute__((address_space(1))) void*)(bga1 + (k0)),            \
          (__attribute__((address_space(3))) void*)(&shm[3 * ASZ + (bo) * BSZ + 4096 + sdst]), 16, 0, 0); }

    // ds_read: logical (row, colbyte=fq*16) -> physical colbyte ^ ((row&3)<<4)
#define RD_A(bo, mi)                                                               \
    (*reinterpret_cast<const bf16x8*>(&shm[(bo) * ASZ +                            \
        (wr * 64 + (mi) * 16 + fr) * BKS +                                         \
        (((fq * 16) ^ (((wr * 64 + (mi) * 16 + fr) & 3) << 4)) >> 1)]))
#define RD_B(bo, ni)                                                               \
    (*reinterpret_cast<const bf16x8*>(&shm[3 * ASZ + (bo) * BSZ +                  \
        (wc * 64 + (ni) * 16 + fr) * BKS +                                         \
        (((fq * 16) ^ (((wc * 64 + (ni) * 16 + fr) & 3) << 4)) >> 1)]))

#define VM3   asm volatile("s_waitcnt vmcnt(3)" ::: "memory")
#define VM0   asm volatile("s_waitcnt vmcnt(0)" ::: "memory")
#define LGKM0 asm volatile("s_waitcnt lgkmcnt(0)" ::: "memory")

    // prologue: stage sets 0 and 1; wait for set 0 only (set 1 stays in flight)
    STAGE(0, 0);
    STAGE(1, BKS);
    VM3;
    __builtin_amdgcn_s_barrier();

    int cur = 0;
    for (int t = 0; t < NTS; ++t) {
        const bool pf2 = (t + 2 < NTS);
        int nx2 = cur + 2; if (nx2 >= 3) nx2 -= 3;
        bf16x8 af[4], bf[4];

#pragma unroll
        for (int i = 0; i < 4; ++i) af[i] = RD_A(cur, i);
#pragma unroll
        for (int j = 0; j < 4; ++j) bf[j] = RD_B(cur, j);
        if (pf2) STAGE(nx2, (t + 2) * BKS);
        LGKM0;
        __builtin_amdgcn_s_setprio(1);
#pragma unroll
        for (int i = 0; i < 4; ++i)
#pragma unroll
            for (int j = 0; j < 4; ++j)
                acc[i][j] = __builtin_amdgcn_mfma_f32_16x16x32_bf16(af[i], bf[j], acc[i][j], 0, 0, 0);
        __builtin_amdgcn_s_setprio(0);
        if (t + 1 < NTS) {
            if (pf2) VM3; else VM0;        // drain set t+1; keep t+2 in flight
            __builtin_amdgcn_s_barrier();
        }
        ++cur; if (cur >= 3) cur = 0;
    }

#undef STAGE
#undef RD_A
#undef RD_B
#undef VM3
#undef VM0
#undef LGKM0

    // ---- epilogue: LDS bounce -> contiguous f32x4 nt stores ----
    float* bnc = reinterpret_cast<float*>(shm);
#pragma unroll
    for (int half = 0; half < 2; ++half) {
        __syncthreads();                    // prior phase reads / K-loop LDS use done
        if (wr == half) {
#pragma unroll
            for (int ni = 0; ni < 4; ++ni) {
                const int col = wc * 64 + ni * 16 + fr;
                const float bv = bias[n0 + col];
#pragma unroll
                for (int mi = 0; mi < 4; ++mi) {
                    const int lr = mi * 16 + fq * 4;
#pragma unroll
                    for (int r = 0; r < 4; ++r)
                        bnc[(lr + r) * 257 + col] = acc[mi][ni][r] + bv;
                }
            }
        }
        __syncthreads();
#pragma unroll
        for (int rr = 0; rr < 8; ++rr) {
            const int lrow = w * 8 + rr;
            const size_t grow = m0 + half * 64 + lrow;
            f32x4 v = *reinterpret_cast<const f32x4*>(&bnc[lrow * 257 + lane * 4]);
            __builtin_nontemporal_store(v,
                reinterpret_cast<f32x4*>(&C[grow * (size_t)BIGN + n0 + lane * 4]));
        }
    }
}

// ---------------- workspace layout (bytes) ----------------
static const size_t O_JOINT = 0;                              // bf16 [65536][640]
static const size_t O_WOUT  = 83886080;                       // bf16 [4096][640]
static const size_t O_ENCLN = 89128960;                       // bf16 [B*T][J]
static const size_t O_DECLN = 90439680;                       // bf16 [B*U][J]
static const size_t O_ENCIN = 90767360;                       // bf16 [T*B][EENC]
static const size_t O_DECIN = 92864512;                       // bf16 [U*B][EDEC]
static const size_t O_WENC  = 93192192;                       // bf16 [J][EENC]
static const size_t O_WDEC  = 94502912;                       // bf16 [J][EDEC]
static const size_t O_EPROJ = 95322112;                       // f32  [T*B][J]
static const size_t O_DPROJ = 97943552;                       // f32  [U*B][J]
static const size_t WS_NEEDED = 98598912;

extern "C" void kernel_launch(void* const* d_in, const int* in_sizes, int n_in,
                              void* d_out, int out_size, void* d_ws, size_t ws_size,
                              hipStream_t stream) {
    const float* enc   = (const float*)d_in[0];
    const float* dec   = (const float*)d_in[1];
    const float* Wenc  = (const float*)d_in[2];
    const float* benc  = (const float*)d_in[3];
    const float* genc  = (const float*)d_in[4];
    const float* beenc = (const float*)d_in[5];
    const float* Wdec  = (const float*)d_in[6];
    const float* bdec  = (const float*)d_in[7];
    const float* gdec  = (const float*)d_in[8];
    const float* bedec = (const float*)d_in[9];
    const float* Wout  = (const float*)d_in[10];
    const float* bout  = (const float*)d_in[11];
    float* out = (float*)d_out;

    if (ws_size < WS_NEEDED) return;

    char* ws = (char*)d_ws;
    u16* joint  = (u16*)(ws + O_JOINT);
    u16* wout_b = (u16*)(ws + O_WOUT);
    u16* encln  = (u16*)(ws + O_ENCLN);
    u16* decln  = (u16*)(ws + O_DECLN);
    u16* encin  = (u16*)(ws + O_ENCIN);
    u16* decin  = (u16*)(ws + O_DECIN);
    u16* wenc_b = (u16*)(ws + O_WENC);
    u16* wdec_b = (u16*)(ws + O_WDEC);
    float* eproj = (float*)(ws + O_EPROJ);
    float* dproj = (float*)(ws + O_DPROJ);

    // 1) bf16 converts
    cvt_bf16<<<1024, 256, 0, stream>>>(enc,  encin,  (T_ * B_ * EENC) / 4);
    cvt_bf16<<<160,  256, 0, stream>>>(dec,  decin,  (U_ * B_ * EDEC) / 4);
    cvt_bf16<<<640,  256, 0, stream>>>(Wenc, wenc_b, (J_ * EENC) / 4);
    cvt_bf16<<<400,  256, 0, stream>>>(Wdec, wdec_b, (J_ * EDEC) / 4);
    cvt_bf16<<<2560, 256, 0, stream>>>(Wout, wout_b, (V_ * J_) / 4);

    // 2) stage-1 projections (bias folded into LN)
    gemm_bt<<<dim3(J_ / 128, (T_ * B_) / 128), 256, 0, stream>>>(encin, wenc_b, eproj, nullptr, EENC, J_);
    gemm_bt<<<dim3(J_ / 128, (U_ * B_) / 128), 256, 0, stream>>>(decin, wdec_b, dproj, nullptr, EDEC, J_);

    // 3) LayerNorm (+bias +affine), transpose to [B, T/U, J], bf16
    ln_kernel<<<T_ * B_, 256, 0, stream>>>(eproj, benc, genc, beenc, encln, B_, T_);
    ln_kernel<<<U_ * B_, 256, 0, stream>>>(dproj, bdec, gdec, bedec, decln, B_, U_);

    // 4) joint = relu(enc + dec) materialized bf16 [B*T*U][J]
    joint_mat<<<(B_ * T_ * U_ * (J_ / 8)) / 256, 256, 0, stream>>>(encln, decln, joint);

    // 5) vocab projection: [65536, 640] x [640, 4096]^T + b_out -> d_out
    gemm_big<<<(B_ * T_ * U_ / 128) * (V_ / 256), 512, 0, stream>>>(joint, wout_b, out, bout);
}